// Round 7
// baseline (706.850 us; speedup 1.0000x reference)
//
#include <hip/hip_runtime.h>

#define H_IN 6144
#define W_IN 6144
#define KH 7
#define KW 7
#define H_OUT (H_IN - KH + 1)   // 6138
#define W_OUT (W_IN - KW + 1)   // 6138

#define TX 64                    // output tile width
#define TY 32                    // output tile height (rows per iteration)
#define RY 8                     // output rows per thread
#define IN_W (TX + KW - 1)       // 70
#define IN_H (TY + KH - 1)       // 38
#define LDS_W 72                 // row stride (floats); 18 float4 per row
#define NV4 18                   // float4 chunks per staged row
#define SHIFT_N (IN_H - TY)      // 6 overlap rows
#define SHIFT_ELT (SHIFT_N * LDS_W)  // 432 floats to roll

#define TILES_PER_BLK 4          // vertical tiles per block (rolling buffer)
#define GX 96                    // x tiles   (96*64  = 6144 >= 6138)
#define GYC 48                   // y chunks  (48*4*32 = 6144 >= 6138)
#define NWG (GX * GYC)           // 4608, divisible by 8
#define NXCD 8

__global__ __launch_bounds__(256, 8) void conv7x7_kernel(
    const float* __restrict__ x,
    const float* __restrict__ wgt,
    const float* __restrict__ bias,
    float* __restrict__ out)
{
    __shared__ float s[IN_H][LDS_W];   // 38*72*4 = 10944 B

    const int tid = threadIdx.x;
    const int tx  = tid & 63;          // 0..63  (x within tile)
    const int tq  = tid >> 6;          // 0..3   (wave id = y-quadrant)

    // ---- XCD-chunked bijective swizzle (NWG % 8 == 0) ----
    const int bid = blockIdx.x;
    const int swz = (bid & (NXCD - 1)) * (NWG / NXCD) + (bid >> 3);
    const int bx  = swz % GX;
    const int byc = swz / GX;

    const int x0    = bx * TX;
    const int ybase = byc * (TY * TILES_PER_BLK);

    const float b = bias[0];           // uniform -> SGPR

    // ---- staging helper: fill LDS rows [r0, IN_H) from input rows gy0+r ----
    auto stage = [&](int r0, int gy0) {
        const int nch = (IN_H - r0) * NV4;
        for (int idx = tid; idx < nch; idx += 256) {
            const int r  = r0 + idx / NV4;
            const int c  = idx % NV4;
            const int gy = gy0 + r;
            const int gx = x0 + (c << 2);
            float4 v = make_float4(0.f, 0.f, 0.f, 0.f);
            if (gy < H_IN) {
                if (gx + 3 < W_IN) {               // aligned interior
                    v = *reinterpret_cast<const float4*>(&x[gy * W_IN + gx]);
                } else {                            // right-edge blocks only
                    float t0 = (gx + 0 < W_IN) ? x[gy * W_IN + gx + 0] : 0.f;
                    float t1 = (gx + 1 < W_IN) ? x[gy * W_IN + gx + 1] : 0.f;
                    float t2 = (gx + 2 < W_IN) ? x[gy * W_IN + gx + 2] : 0.f;
                    float t3 = (gx + 3 < W_IN) ? x[gy * W_IN + gx + 3] : 0.f;
                    v = make_float4(t0, t1, t2, t3);
                }
            }
            *reinterpret_cast<float4*>(&s[r][c << 2]) = v;
        }
    };

    // ---- prologue: full 38-row stage for tile 0 ----
    stage(0, ybase);
    __syncthreads();

    for (int t = 0; t < TILES_PER_BLK; ++t) {
        const int y0 = ybase + t * TY;

        // ---- compute: 8 output rows per thread, sliding vertical window ----
        float acc[RY];
#pragma unroll
        for (int r = 0; r < RY; ++r) acc[r] = 0.f;

        const int ry0 = tq * RY;

#pragma unroll
        for (int kx = 0; kx < KW; ++kx) {
            float v[RY + KH - 1];              // 14-row vertical window
#pragma unroll
            for (int j = 0; j < RY + KH - 1; ++j)
                v[j] = s[ry0 + j][tx + kx];
#pragma unroll
            for (int ky = 0; ky < KH; ++ky) {
                const float wv = wgt[ky * KW + kx];   // uniform s_load (SGPR)
#pragma unroll
                for (int r = 0; r < RY; ++r)
                    acc[r] = fmaf(wv, v[r + ky], acc[r]);
            }
        }

        // ---- epilogue: bias + coalesced stores (256B contiguous per wave) ----
        const int ox = x0 + tx;
        if (ox < W_OUT) {
#pragma unroll
            for (int r = 0; r < RY; ++r) {
                const int oy = y0 + ry0 + r;
                if (oy < H_OUT) out[oy * W_OUT + ox] = acc[r] + b;
            }
        }

        // ---- roll buffer: rows 32..37 -> 0..5, stage 32 new rows ----
        if (t + 1 < TILES_PER_BLK) {
            const int i2 = tid + 256;
            // FIX(R5): source rows are TY+0..TY+5 (32..37). Previous code read
            // s[SHIFT_N+TY+...] = rows 38..43 — past the array end (OOB garbage).
            float sh0 = s[TY + tid / LDS_W][tid % LDS_W];
            float sh1 = 0.f;
            if (i2 < SHIFT_ELT) sh1 = s[TY + i2 / LDS_W][i2 % LDS_W];
            __syncthreads();                    // compute + shift-reads done
            s[tid / LDS_W][tid % LDS_W] = sh0;
            if (i2 < SHIFT_ELT) s[i2 / LDS_W][i2 % LDS_W] = sh1;
            stage(SHIFT_N, y0 + TY);            // rows 6..37 <- next 32 rows
            __syncthreads();                    // stage visible for next iter
        }
    }
}

extern "C" void kernel_launch(void* const* d_in, const int* in_sizes, int n_in,
                              void* d_out, int out_size, void* d_ws, size_t ws_size,
                              hipStream_t stream) {
    const float* x    = (const float*)d_in[0];
    const float* wgt  = (const float*)d_in[1];
    const float* bias = (const float*)d_in[2];
    float* out        = (float*)d_out;

    conv7x7_kernel<<<dim3(NWG), dim3(256), 0, stream>>>(x, wgt, bias, out);
}

// Round 13
// 295.395 us; speedup vs baseline: 2.3929x; 2.3929x over previous
//
#include <hip/hip_runtime.h>

#define H_IN 6144
#define W_IN 6144
#define KH 7
#define KW 7
#define H_OUT (H_IN - KH + 1)   // 6138
#define W_OUT (W_IN - KW + 1)   // 6138

#define TX 64                    // output tile width
#define TY 32                    // output tile height (rows per iteration)
#define RY 8                     // output rows per thread
#define IN_W (TX + KW - 1)       // 70
#define IN_H (TY + KH - 1)       // 38
#define LDS_W 72                 // row stride (floats); 18 float4 per row
#define NV4 18                   // float4 chunks per staged row
#define SHIFT_N (IN_H - TY)      // 6 overlap rows
#define SHIFT_ELT (SHIFT_N * LDS_W)  // 432 floats to roll

#define TILES_PER_BLK 4          // vertical tiles per block (rolling buffer)
#define GX 96                    // x tiles   (96*64  = 6144 >= 6138)
#define GYC 48                   // y chunks  (48*4*32 = 6144 >= 6138)
#define NWG (GX * GYC)           // 4608, divisible by 8
#define NXCD 8

// R7 lesson: (256,8) forced VGPR=32 -> acc[8]+v[14] spilled to scratch,
// +1 GB HBM traffic, 537us. (256,4) caps at 128 VGPR; compiler uses ~64,
// which still allows 8 waves/SIMD -- occupancy via grid shape, not regalloc.
__global__ __launch_bounds__(256, 4) void conv7x7_kernel(
    const float* __restrict__ x,
    const float* __restrict__ wgt,
    const float* __restrict__ bias,
    float* __restrict__ out)
{
    __shared__ float s[IN_H][LDS_W];   // 38*72*4 = 10944 B

    const int tid = threadIdx.x;
    const int tx  = tid & 63;          // 0..63  (x within tile)
    const int tq  = tid >> 6;          // 0..3   (wave id = y-quadrant)

    // ---- XCD-chunked bijective swizzle (NWG % 8 == 0) ----
    const int bid = blockIdx.x;
    const int swz = (bid & (NXCD - 1)) * (NWG / NXCD) + (bid >> 3);
    const int bx  = swz % GX;
    const int byc = swz / GX;

    const int x0    = bx * TX;
    const int ybase = byc * (TY * TILES_PER_BLK);

    const float b = bias[0];           // uniform -> SGPR

    // ---- staging helper: fill LDS rows [r0, IN_H) from input rows gy0+r ----
    auto stage = [&](int r0, int gy0) {
        const int nch = (IN_H - r0) * NV4;
        for (int idx = tid; idx < nch; idx += 256) {
            const int r  = r0 + idx / NV4;
            const int c  = idx % NV4;
            const int gy = gy0 + r;
            const int gx = x0 + (c << 2);
            float4 v = make_float4(0.f, 0.f, 0.f, 0.f);
            if (gy < H_IN) {
                if (gx + 3 < W_IN) {               // aligned interior
                    v = *reinterpret_cast<const float4*>(&x[gy * W_IN + gx]);
                } else {                            // right-edge blocks only
                    float t0 = (gx + 0 < W_IN) ? x[gy * W_IN + gx + 0] : 0.f;
                    float t1 = (gx + 1 < W_IN) ? x[gy * W_IN + gx + 1] : 0.f;
                    float t2 = (gx + 2 < W_IN) ? x[gy * W_IN + gx + 2] : 0.f;
                    float t3 = (gx + 3 < W_IN) ? x[gy * W_IN + gx + 3] : 0.f;
                    v = make_float4(t0, t1, t2, t3);
                }
            }
            *reinterpret_cast<float4*>(&s[r][c << 2]) = v;
        }
    };

    // ---- prologue: full 38-row stage for tile 0 ----
    stage(0, ybase);
    __syncthreads();

    for (int t = 0; t < TILES_PER_BLK; ++t) {
        const int y0 = ybase + t * TY;

        // ---- compute: 8 output rows per thread, sliding vertical window ----
        float acc[RY];
#pragma unroll
        for (int r = 0; r < RY; ++r) acc[r] = 0.f;

        const int ry0 = tq * RY;

#pragma unroll
        for (int kx = 0; kx < KW; ++kx) {
            float v[RY + KH - 1];              // 14-row vertical window
#pragma unroll
            for (int j = 0; j < RY + KH - 1; ++j)
                v[j] = s[ry0 + j][tx + kx];
#pragma unroll
            for (int ky = 0; ky < KH; ++ky) {
                const float wv = wgt[ky * KW + kx];   // uniform s_load (SGPR)
#pragma unroll
                for (int r = 0; r < RY; ++r)
                    acc[r] = fmaf(wv, v[r + ky], acc[r]);
            }
        }

        // ---- epilogue: bias + coalesced stores (256B contiguous per wave) ----
        const int ox = x0 + tx;
        if (ox < W_OUT) {
#pragma unroll
            for (int r = 0; r < RY; ++r) {
                const int oy = y0 + ry0 + r;
                if (oy < H_OUT) out[oy * W_OUT + ox] = acc[r] + b;
            }
        }

        // ---- roll buffer: rows 32..37 -> 0..5, stage 32 new rows ----
        if (t + 1 < TILES_PER_BLK) {
            const int i2 = tid + 256;
            float sh0 = s[TY + tid / LDS_W][tid % LDS_W];   // rows 32..37
            float sh1 = 0.f;
            if (i2 < SHIFT_ELT) sh1 = s[TY + i2 / LDS_W][i2 % LDS_W];
            __syncthreads();                    // compute + shift-reads done
            s[tid / LDS_W][tid % LDS_W] = sh0;
            if (i2 < SHIFT_ELT) s[i2 / LDS_W][i2 % LDS_W] = sh1;
            stage(SHIFT_N, y0 + TY);            // rows 6..37 <- next 32 rows
            __syncthreads();                    // stage visible for next iter
        }
    }
}

extern "C" void kernel_launch(void* const* d_in, const int* in_sizes, int n_in,
                              void* d_out, int out_size, void* d_ws, size_t ws_size,
                              hipStream_t stream) {
    const float* x    = (const float*)d_in[0];
    const float* wgt  = (const float*)d_in[1];
    const float* bias = (const float*)d_in[2];
    float* out        = (float*)d_out;

    conv7x7_kernel<<<dim3(NWG), dim3(256), 0, stream>>>(x, wgt, bias, out);
}

// Round 16
// 291.504 us; speedup vs baseline: 2.4248x; 1.0133x over previous
//
#include <hip/hip_runtime.h>

#define H_IN 6144
#define W_IN 6144
#define KH 7
#define KW 7
#define H_OUT (H_IN - KH + 1)   // 6138
#define W_OUT (W_IN - KW + 1)   // 6138

#define TX 64                    // output tile width
#define TY 32                    // output tile height (rows per iteration)
#define RY 8                     // output rows per thread
#define IN_W (TX + KW - 1)       // 70
#define IN_H (TY + KH - 1)       // 38
#define LDS_W 72                 // row stride (floats); 18 float4 per row
#define NV4 18                   // float4 chunks per staged row
#define LDS_ROWS 64              // circular row window (pow2) -> slot = row & 63

#define TILES_PER_BLK 4          // vertical tiles per block
#define GX 96                    // x tiles
#define GYC 48                   // y chunks (48*128 = 6144)
#define NWG (GX * GYC)           // 4608, divisible by 8
#define NXCD 8

#define CH_TILE (TY * NV4)       // 576 float4 chunks per 32-row stage
#define MAXCH 3                  // ceil(576/256) chunks per thread

// R7: (256,8) forced VGPR=32 -> spills, +1GB scratch traffic. Keep (256,4).
// R13: 4608-block rolling grid hit 119.6us; WRITE fixed to ~148MB; latency-
// bound (VALU 52%, HBM 24%, occ 39%). R14: async-stage into regs (T14) +
// circular LDS window removes stage latency + roll from the critical path.
__global__ __launch_bounds__(256, 4) void conv7x7_kernel(
    const float* __restrict__ x,
    const float* __restrict__ wgt,
    const float* __restrict__ bias,
    float* __restrict__ out)
{
    __shared__ float s[LDS_ROWS][LDS_W];   // 64*72*4 = 18432 B

    const int tid = threadIdx.x;
    const int tx  = tid & 63;          // 0..63  (x within tile)
    const int tq  = tid >> 6;          // 0..3   (wave id = y-quadrant)

    // ---- XCD-chunked bijective swizzle (NWG % 8 == 0) ----
    const int bid = blockIdx.x;
    const int swz = (bid & (NXCD - 1)) * (NWG / NXCD) + (bid >> 3);
    const int bx  = swz % GX;
    const int byc = swz / GX;

    const int x0    = bx * TX;
    const int ybase = byc * (TY * TILES_PER_BLK);   // multiple of 128

    const float b = bias[0];           // uniform -> SGPR

    // ---- global float4 fetch with edge guards ----
    auto fetch = [&](int gy, int gx) -> float4 {
        float4 v = make_float4(0.f, 0.f, 0.f, 0.f);
        if (gy < H_IN) {
            if (gx + 3 < W_IN) {
                v = *reinterpret_cast<const float4*>(&x[gy * W_IN + gx]);
            } else {
                float t0 = (gx + 0 < W_IN) ? x[gy * W_IN + gx + 0] : 0.f;
                float t1 = (gx + 1 < W_IN) ? x[gy * W_IN + gx + 1] : 0.f;
                float t2 = (gx + 2 < W_IN) ? x[gy * W_IN + gx + 2] : 0.f;
                float t3 = (gx + 3 < W_IN) ? x[gy * W_IN + gx + 3] : 0.f;
                v = make_float4(t0, t1, t2, t3);
            }
        }
        return v;
    };

    // ---- prologue: local rows 0..37 -> slots 0..37 ----
    for (int idx = tid; idx < IN_H * NV4; idx += 256) {
        const int r = idx / NV4;
        const int c = idx % NV4;
        float4 v = fetch(ybase + r, x0 + (c << 2));
        *reinterpret_cast<float4*>(&s[r][c << 2]) = v;
    }
    __syncthreads();

    for (int t = 0; t < TILES_PER_BLK; ++t) {
        const int y0 = ybase + t * TY;
        const int l0 = (t & 1) * TY;           // (32t) & 63

        // ---- issue next tile's 32 rows into registers (latency hides
        //      under the FMA block below; vmcnt waited at the ds_write) ----
        float4 stg[MAXCH];
        const bool do_stage = (t + 1 < TILES_PER_BLK);
        if (do_stage) {
#pragma unroll
            for (int k = 0; k < MAXCH; ++k) {
                const int idx = tid + (k << 8);
                if (idx < CH_TILE) {
                    const int r = idx / NV4;
                    const int c = idx % NV4;
                    stg[k] = fetch(y0 + IN_H + r, x0 + (c << 2));
                }
            }
        }

        // ---- compute: 8 output rows per thread, sliding vertical window ----
        float acc[RY];
#pragma unroll
        for (int r = 0; r < RY; ++r) acc[r] = 0.f;

        const int ry0 = tq * RY;

#pragma unroll
        for (int kx = 0; kx < KW; ++kx) {
            float v[RY + KH - 1];              // 14-row vertical window
#pragma unroll
            for (int j = 0; j < RY + KH - 1; ++j)
                v[j] = s[(l0 + ry0 + j) & (LDS_ROWS - 1)][tx + kx];
#pragma unroll
            for (int ky = 0; ky < KH; ++ky) {
                const float wv = wgt[ky * KW + kx];   // uniform s_load (SGPR)
#pragma unroll
                for (int r = 0; r < RY; ++r)
                    acc[r] = fmaf(wv, v[r + ky], acc[r]);
            }
        }

        // ---- epilogue: bias + coalesced stores ----
        const int ox = x0 + tx;
        if (ox < W_OUT) {
#pragma unroll
            for (int r = 0; r < RY; ++r) {
                const int oy = y0 + ry0 + r;
                if (oy < H_OUT) out[oy * W_OUT + ox] = acc[r] + b;
            }
        }

        // ---- commit staged rows: slots (l0+38+r)&63 overwrite only rows
        //      <= y0+5, which are dead after this tile's compute ----
        if (do_stage) {
            __syncthreads();                   // all compute reads done
#pragma unroll
            for (int k = 0; k < MAXCH; ++k) {
                const int idx = tid + (k << 8);
                if (idx < CH_TILE) {
                    const int r    = idx / NV4;
                    const int c    = idx % NV4;
                    const int slot = (l0 + IN_H + r) & (LDS_ROWS - 1);
                    *reinterpret_cast<float4*>(&s[slot][c << 2]) = stg[k];
                }
            }
            __syncthreads();                   // staged rows visible
        }
    }
}

extern "C" void kernel_launch(void* const* d_in, const int* in_sizes, int n_in,
                              void* d_out, int out_size, void* d_ws, size_t ws_size,
                              hipStream_t stream) {
    const float* x    = (const float*)d_in[0];
    const float* wgt  = (const float*)d_in[1];
    const float* bias = (const float*)d_in[2];
    float* out        = (float*)d_out;

    conv7x7_kernel<<<dim3(NWG), dim3(256), 0, stream>>>(x, wgt, bias, out);
}